// Round 1
// baseline (233.642 us; speedup 1.0000x reference)
//
#include <hip/hip_runtime.h>
#include <math.h>

// Problem constants (from reference)
constexpr int B_ = 8;
constexpr int N_ = 8192;
constexpr int K_ = 48;
constexpr int NFREQ = 8;    // NUM_POS/2
constexpr int NEDGE = 16;
constexpr int FANIN = 23;   // NUM_POS + 7
constexpr float EPSF = 1e-12f;

// ---------------- helpers ----------------
struct F3 { float x, y, z; };

__device__ inline F3 f3(float a, float b, float c) { F3 r{a,b,c}; return r; }
__device__ inline F3 sub3(F3 a, F3 b) { return f3(a.x-b.x, a.y-b.y, a.z-b.z); }
__device__ inline F3 cross3(F3 a, F3 b) {
    return f3(a.y*b.z - a.z*b.y, a.z*b.x - a.x*b.z, a.x*b.y - a.y*b.x);
}
__device__ inline F3 norm3(F3 a) {
    float n = sqrtf(a.x*a.x + a.y*a.y + a.z*a.z);
    float inv = 1.0f / fmaxf(n, EPSF);
    return f3(a.x*inv, a.y*inv, a.z*inv);
}
__device__ inline float signf0(float x) {
    return (x > 0.0f) ? 1.0f : ((x < 0.0f) ? -1.0f : 0.0f);
}

// ---------------- kernel 1: per-node orientation frames ----------------
// O[b,n,9] = rows [o_1; n_2; cross(o_1,n_2)], zero at n==0, n>=N-2.
__global__ void compute_O_kernel(const float* __restrict__ X, float* __restrict__ O) {
    int idx = blockIdx.x * blockDim.x + threadIdx.x;
    if (idx >= B_ * N_) return;
    int n = idx & (N_ - 1);
    float* o9 = O + (size_t)idx * 9;
    if (n == 0 || n >= N_ - 2) {
        #pragma unroll
        for (int i = 0; i < 9; i++) o9[i] = 0.0f;
        return;
    }
    const float* Xp = X + (size_t)idx * 3;
    F3 xm = f3(Xp[-3], Xp[-2], Xp[-1]);
    F3 x0 = f3(Xp[0], Xp[1], Xp[2]);
    F3 xp = f3(Xp[3], Xp[4], Xp[5]);
    F3 u2 = norm3(sub3(x0, xm));   // U[i-1]
    F3 u1 = norm3(sub3(xp, x0));   // U[i]
    F3 n2 = norm3(cross3(u2, u1));
    F3 o1 = norm3(sub3(u2, u1));
    F3 c  = cross3(o1, n2);
    o9[0] = o1.x; o9[1] = o1.y; o9[2] = o1.z;
    o9[3] = n2.x; o9[4] = n2.y; o9[5] = n2.z;
    o9[6] = c.x;  o9[7] = c.y;  o9[8] = c.z;
}

// ---------------- kernel 2: per-edge features + matvec + ssq reduce ----------------
// block: 256 threads = 256 consecutive n, fixed (b,k). grid = B*K*(N/256), k fastest.
__launch_bounds__(256)
__global__ void edge_kernel(const float* __restrict__ X, const int* __restrict__ Eidx,
                            const float* __restrict__ O, const float* __restrict__ tfrq,
                            const float* __restrict__ ts, const float* __restrict__ W,
                            const float* __restrict__ bias, float* __restrict__ out,
                            float* __restrict__ acc) {
    constexpr int NCH = N_ / 256;  // 32 chunks
    int bid = blockIdx.x;
    int k = bid % K_;
    int chunk = (bid / K_) % NCH;
    int b = bid / (K_ * NCH);
    int tid = threadIdx.x;
    int n = chunk * 256 + tid;

    __shared__ float sW[NEDGE][FANIN];
    __shared__ float sB[NEDGE];
    __shared__ float sFR[NFREQ];
    __shared__ float sAcc[4][NEDGE];

    for (int i = tid; i < NEDGE * FANIN; i += 256) sW[i / FANIN][i % FANIN] = W[i];
    if (tid < NEDGE) sB[tid] = bias[tid];
    if (tid < NFREQ) sFR[tid] = tfrq[tid] * ts[0];
    __syncthreads();

    size_t node = (size_t)b * N_ + n;
    int j = Eidx[node * K_ + k];
    size_t nodej = (size_t)b * N_ + j;

    float Xn[3], Xj[3], Os[9], Oj[9];
    #pragma unroll
    for (int i = 0; i < 3; i++) { Xn[i] = X[node * 3 + i]; Xj[i] = X[nodej * 3 + i]; }
    #pragma unroll
    for (int i = 0; i < 9; i++) { Os[i] = O[node * 9 + i]; Oj[i] = O[nodej * 9 + i]; }

    // dU = l2norm(Of @ dXn)
    float dX0 = Xj[0] - Xn[0], dX1 = Xj[1] - Xn[1], dX2 = Xj[2] - Xn[2];
    float v0 = Os[0]*dX0 + Os[1]*dX1 + Os[2]*dX2;
    float v1 = Os[3]*dX0 + Os[4]*dX1 + Os[5]*dX2;
    float v2 = Os[6]*dX0 + Os[7]*dX1 + Os[8]*dX2;
    float vn = sqrtf(v0*v0 + v1*v1 + v2*v2);
    float vinv = 1.0f / fmaxf(vn, EPSF);
    float dU0 = v0*vinv, dU1 = v1*vinv, dU2 = v2*vinv;

    // R = Os^T * Oj  (R[i][l] = sum_j Os[3j+i] * Oj[3j+l])
    float R[3][3];
    #pragma unroll
    for (int i = 0; i < 3; i++)
        #pragma unroll
        for (int l = 0; l < 3; l++)
            R[i][l] = Os[i]*Oj[l] + Os[3+i]*Oj[3+l] + Os[6+i]*Oj[6+l];

    float Rxx = R[0][0], Ryy = R[1][1], Rzz = R[2][2];
    float mg0 = 0.5f * sqrtf(fabsf(1.0f + Rxx - Ryy - Rzz) + EPSF);
    float mg1 = 0.5f * sqrtf(fabsf(1.0f - Rxx + Ryy - Rzz) + EPSF);
    float mg2 = 0.5f * sqrtf(fabsf(1.0f - Rxx - Ryy + Rzz) + EPSF);
    float qx = signf0(R[2][1] - R[1][2]) * mg0;
    float qy = signf0(R[0][2] - R[2][0]) * mg1;
    float qz = signf0(R[1][0] - R[0][1]) * mg2;
    float qw = 0.5f * sqrtf(fmaxf(1.0f + Rxx + Ryy + Rzz, 0.0f) + EPSF);
    float qn = sqrtf(qx*qx + qy*qy + qz*qz + qw*qw);
    float qinv = 1.0f / fmaxf(qn, EPSF);
    qx *= qinv; qy *= qinv; qz *= qinv; qw *= qinv;

    // features: [sin x8, cos x8, dU x3, Q x4]
    float feats[FANIN];
    float d = (float)j - (float)n;
    #pragma unroll
    for (int f = 0; f < NFREQ; f++) {
        float s, c;
        sincosf(d * sFR[f], &s, &c);
        feats[f] = s;
        feats[f + NFREQ] = c;
    }
    feats[16] = dU0; feats[17] = dU1; feats[18] = dU2;
    feats[19] = qx;  feats[20] = qy;  feats[21] = qz;  feats[22] = qw;

    // h = W @ feats + b
    float h[NEDGE];
    #pragma unroll
    for (int o = 0; o < NEDGE; o++) {
        float a = sB[o];
        #pragma unroll
        for (int f = 0; f < FANIN; f++) a = fmaf(feats[f], sW[o][f], a);
        h[o] = a;
    }

    // store unnormalized
    size_t base = (node * K_ + k) * 16;
    #pragma unroll
    for (int q = 0; q < 4; q++) {
        float4 val = make_float4(h[4*q], h[4*q+1], h[4*q+2], h[4*q+3]);
        *reinterpret_cast<float4*>(out + base + 4*q) = val;
    }

    // sum of squares over n: wave shuffle reduce, then LDS across 4 waves
    int lane = tid & 63, wid = tid >> 6;
    #pragma unroll
    for (int o = 0; o < NEDGE; o++) {
        float vsq = h[o] * h[o];
        #pragma unroll
        for (int m = 1; m < 64; m <<= 1) vsq += __shfl_xor(vsq, m, 64);
        if (lane == 0) sAcc[wid][o] = vsq;
    }
    __syncthreads();
    if (tid < NEDGE) {
        float t = sAcc[0][tid] + sAcc[1][tid] + sAcc[2][tid] + sAcc[3][tid];
        atomicAdd(&acc[((size_t)b * K_ + k) * NEDGE + tid], t);
    }
}

// ---------------- kernel 3a: reciprocal norms ----------------
__global__ void inv_kernel(const float* __restrict__ acc, float* __restrict__ rinv) {
    int i = blockIdx.x * blockDim.x + threadIdx.x;
    if (i >= B_ * K_ * NEDGE) return;
    rinv[i] = 1.0f / fmaxf(sqrtf(acc[i]), EPSF);
}

// ---------------- kernel 3b: rescale output ----------------
__launch_bounds__(256)
__global__ void scale_kernel(float* __restrict__ out, const float* __restrict__ rinv) {
    size_t idx = (size_t)blockIdx.x * blockDim.x + threadIdx.x;  // float4 index
    constexpr size_t TOTAL4 = (size_t)B_ * N_ * K_ * 4;          // elements/4
    if (idx >= TOTAL4) return;
    size_t e0 = idx * 4;
    unsigned int o0 = (unsigned int)(e0 & 15);
    unsigned int key = (unsigned int)(e0 >> 4);       // (b*N+n)*K + k
    unsigned int k = key % (unsigned int)K_;
    unsigned int b = key / (unsigned int)(N_ * K_);
    const float* rp = rinv + ((size_t)b * K_ + k) * 16 + o0;
    float4 vv = *reinterpret_cast<float4*>(out + e0);
    vv.x *= rp[0]; vv.y *= rp[1]; vv.z *= rp[2]; vv.w *= rp[3];
    *reinterpret_cast<float4*>(out + e0) = vv;
}

// ---------------- launch ----------------
extern "C" void kernel_launch(void* const* d_in, const int* in_sizes, int n_in,
                              void* d_out, int out_size, void* d_ws, size_t ws_size,
                              hipStream_t stream) {
    const float* X    = (const float*)d_in[0];   // p (B,N,3)
    const int*   E    = (const int*)d_in[1];     // e_idx (B,N,K)
    // d_in[2] = mask (unused by reference)
    const float* tfrq = (const float*)d_in[3];   // (8,)
    const float* ts   = (const float*)d_in[4];   // scalar
    const float* W    = (const float*)d_in[5];   // (16,23)
    const float* bias = (const float*)d_in[6];   // (16,)
    float* out = (float*)d_out;

    float* O    = (float*)d_ws;                          // B*N*9 floats = 9.44 MB
    float* acc  = O + (size_t)B_ * N_ * 9;               // B*K*16 = 6144 floats
    float* rinv = acc + B_ * K_ * NEDGE;                 // 6144 floats

    hipMemsetAsync(acc, 0, (size_t)B_ * K_ * NEDGE * sizeof(float), stream);

    compute_O_kernel<<<(B_ * N_ + 255) / 256, 256, 0, stream>>>(X, O);
    edge_kernel<<<B_ * K_ * (N_ / 256), 256, 0, stream>>>(X, E, O, tfrq, ts, W, bias, out, acc);
    inv_kernel<<<(B_ * K_ * NEDGE + 255) / 256, 256, 0, stream>>>(acc, rinv);

    constexpr size_t TOTAL4 = (size_t)B_ * N_ * K_ * 4;
    scale_kernel<<<(TOTAL4 + 255) / 256, 256, 0, stream>>>(out, rinv);
}